// Round 4
// baseline (107.586 us; speedup 1.0000x reference)
//
#include <hip/hip_runtime.h>
#include <math.h>

// Reference: B=256; upsample 64/32/16 -> 256x256 (bilinear, align_corners=True), sum -> maps;
// 5x5 gaussian blur (sigma=4, reflect); per-sample max -> scores.
// d_out: [0:B] scores, [B:] maps (B*256*256).
//
// Round-4 structure: lane owns 4 consecutive columns -> a wave (64 lanes) covers a full
// 256-wide row. Horizontal 5-tap via 4 __shfl from adjacent lanes (NO vsm, NO barriers
// in main loop). Map stores are float4. Vertical 5-tap in a register window. Rolling
// separable bilinear per column (y-counters lane-uniform -> SGPR). Each wave handles a
// 16-row strip; grid = B*4 blocks x 4 waves. Partial maxes -> d_ws (no atomics), then
// a tiny deterministic reduce kernel. Pure function of inputs every call.

static constexpr int W     = 256;
static constexpr int QH    = 4;    // blocks per sample
static constexpr int WAVES = 4;    // waves per block
static constexpr int RW    = 16;   // rows per wave

__device__ __forceinline__ int reflect256(int i) {
    if (i < 0) i = -i;
    if (i > 255) i = 510 - i;
    return i;
}

__global__ __launch_bounds__(256, 4) void fused_kernel(
    const float* __restrict__ in0,   // [B,64,64]
    const float* __restrict__ in1,   // [B,32,32]
    const float* __restrict__ in2,   // [B,16,16]
    float* __restrict__ part,        // [B*QH*WAVES]
    float* __restrict__ maps)        // [B,256,256]
{
    const int t    = threadIdx.x;
    const int lane = t & 63;
    const int w    = t >> 6;
    const int bid  = blockIdx.x;
    const int b    = bid >> 2;
    const int R0   = (bid & 3) * (WAVES * RW) + w * RW;   // first owned row of this wave

    __shared__ float s0[64 * 64];   // 16 KB
    __shared__ float s1[32 * 32];   // 4 KB
    __shared__ float s2[16 * 16];   // 1 KB

    // ---- stage inputs (float4) ----
    {
        const float4* g0 = (const float4*)(in0 + (size_t)b * 4096);
        const float4* g1 = (const float4*)(in1 + (size_t)b * 1024);
        float4* l0 = (float4*)s0;
#pragma unroll
        for (int i = 0; i < 4; ++i) l0[t + i * 256] = g0[t + i * 256];
        ((float4*)s1)[t] = g1[t];
        if (t < 64) ((float4*)s2)[t] = ((const float4*)(in2 + (size_t)b * 256))[t];
    }
    __syncthreads();

    const float inv255 = 1.0f / 255.0f;

    // ---- per-column x params; lane owns cols c = 4*lane + j ----
    int   xa0[4], xb0[4], xa1[4], xb1[4], xa2[4], xb2[4];
    float fx0[4], fx1[4], fx2[4];
#pragma unroll
    for (int j = 0; j < 4; ++j) {
        int c = 4 * lane + j;
        int ix = c * 63; int x0 = ix / 255; fx0[j] = (float)(ix - 255 * x0) * inv255;
        xa0[j] = x0; xb0[j] = min(x0 + 1, 63);
        ix = c * 31; x0 = ix / 255; fx1[j] = (float)(ix - 255 * x0) * inv255;
        xa1[j] = x0; xb1[j] = min(x0 + 1, 31);
        ix = c * 15; x0 = ix / 255; fx2[j] = (float)(ix - 255 * x0) * inv255;
        xa2[j] = x0; xb2[j] = min(x0 + 1, 15);
    }

    // ---- gaussian weights (ksize=5, sigma=4) ----
    const float e1  = expf(-1.0f / 32.0f);
    const float e2  = expf(-4.0f / 32.0f);
    const float nrm = 1.0f + 2.0f * e1 + 2.0f * e2;
    const float wc = 1.0f / nrm, wa = e1 / nrm, wb = e2 / nrm;

    // full bilinear sample of map row rn (reflected), for halo rows outside [0,255]
    auto direct_row = [&](int rn, float out[4]) {
        int ry = reflect256(rn);
        int iy = ry * 63; int y0 = iy / 255; float fy = (float)(iy - 255 * y0) * inv255;
        int y1 = min(y0 + 1, 63);
#pragma unroll
        for (int j = 0; j < 4; ++j) {
            float a = s0[y0 * 64 + xa0[j]], bb = s0[y0 * 64 + xb0[j]];
            float c = s0[y1 * 64 + xa0[j]], d  = s0[y1 * 64 + xb0[j]];
            float top = a + fx0[j] * (bb - a), bot = c + fx0[j] * (d - c);
            out[j] = top + fy * (bot - top);
        }
        iy = ry * 31; y0 = iy / 255; fy = (float)(iy - 255 * y0) * inv255; y1 = min(y0 + 1, 31);
#pragma unroll
        for (int j = 0; j < 4; ++j) {
            float a = s1[y0 * 32 + xa1[j]], bb = s1[y0 * 32 + xb1[j]];
            float c = s1[y1 * 32 + xa1[j]], d  = s1[y1 * 32 + xb1[j]];
            float top = a + fx1[j] * (bb - a), bot = c + fx1[j] * (d - c);
            out[j] += top + fy * (bot - top);
        }
        iy = ry * 15; y0 = iy / 255; fy = (float)(iy - 255 * y0) * inv255; y1 = min(y0 + 1, 15);
#pragma unroll
        for (int j = 0; j < 4; ++j) {
            float a = s2[y0 * 16 + xa2[j]], bb = s2[y0 * 16 + xb2[j]];
            float c = s2[y1 * 16 + xa2[j]], d  = s2[y1 * 16 + xb2[j]];
            float top = a + fx2[j] * (bb - a), bot = c + fx2[j] * (d - c);
            out[j] += top + fy * (bot - top);
        }
    };

    // ---- rolling bilinear state, initialized at rstart = max(R0-2, 0) ----
    const int rs = max(R0 - 2, 0);
    int ya, yb, yc, ra, rb, rc;
    float lo0[4], hi0[4], lo1[4], hi1[4], lo2[4], hi2[4];
    {
        int iy = rs * 63; ya = iy / 255; ra = iy - 255 * ya; int yn = min(ya + 1, 63);
#pragma unroll
        for (int j = 0; j < 4; ++j) {
            float a = s0[ya * 64 + xa0[j]], bb = s0[ya * 64 + xb0[j]];
            lo0[j] = a + fx0[j] * (bb - a);
            a = s0[yn * 64 + xa0[j]]; bb = s0[yn * 64 + xb0[j]];
            hi0[j] = a + fx0[j] * (bb - a);
        }
        iy = rs * 31; yb = iy / 255; rb = iy - 255 * yb; yn = min(yb + 1, 31);
#pragma unroll
        for (int j = 0; j < 4; ++j) {
            float a = s1[yb * 32 + xa1[j]], bb = s1[yb * 32 + xb1[j]];
            lo1[j] = a + fx1[j] * (bb - a);
            a = s1[yn * 32 + xa1[j]]; bb = s1[yn * 32 + xb1[j]];
            hi1[j] = a + fx1[j] * (bb - a);
        }
        iy = rs * 15; yc = iy / 255; rc = iy - 255 * yc; yn = min(yc + 1, 15);
#pragma unroll
        for (int j = 0; j < 4; ++j) {
            float a = s2[yc * 16 + xa2[j]], bb = s2[yc * 16 + xb2[j]];
            lo2[j] = a + fx2[j] * (bb - a);
            a = s2[yn * 16 + xa2[j]]; bb = s2[yn * 16 + xb2[j]];
            hi2[j] = a + fx2[j] * (bb - a);
        }
    }

    float* __restrict__ mrow = maps + (size_t)b * W * W;
    float m0[4], m1[4], m2[4], m3[4];
    float gmax = -INFINITY;

    for (int i = 0; i < RW + 4; ++i) {
        const int rn = R0 - 2 + i;
        float mn[4];
        if (rn < 0 || rn > 255) {          // wave-uniform: only first/last strip
            direct_row(rn, mn);
        } else {
            const float f0 = (float)ra * inv255;
            const float f1 = (float)rb * inv255;
            const float f2 = (float)rc * inv255;
#pragma unroll
            for (int j = 0; j < 4; ++j)
                mn[j] = (lo0[j] + f0 * (hi0[j] - lo0[j]))
                      + (lo1[j] + f1 * (hi1[j] - lo1[j]))
                      + (lo2[j] + f2 * (hi2[j] - lo2[j]));
            // advance (uniform; step < 1 so at most one increment each)
            ra += 63;
            if (ra >= 255) {
                ra -= 255; ++ya; int yn = min(ya + 1, 63);
#pragma unroll
                for (int j = 0; j < 4; ++j) {
                    lo0[j] = hi0[j];
                    float a = s0[yn * 64 + xa0[j]], bb = s0[yn * 64 + xb0[j]];
                    hi0[j] = a + fx0[j] * (bb - a);
                }
            }
            rb += 31;
            if (rb >= 255) {
                rb -= 255; ++yb; int yn = min(yb + 1, 31);
#pragma unroll
                for (int j = 0; j < 4; ++j) {
                    lo1[j] = hi1[j];
                    float a = s1[yn * 32 + xa1[j]], bb = s1[yn * 32 + xb1[j]];
                    hi1[j] = a + fx1[j] * (bb - a);
                }
            }
            rc += 15;
            if (rc >= 255) {
                rc -= 255; ++yc; int yn = min(yc + 1, 15);
#pragma unroll
                for (int j = 0; j < 4; ++j) {
                    lo2[j] = hi2[j];
                    float a = s2[yn * 16 + xa2[j]], bb = s2[yn * 16 + xb2[j]];
                    hi2[j] = a + fx2[j] * (bb - a);
                }
            }
        }

        if (i >= 2 && i < 2 + RW) {        // own rows: write maps once, float4
            *(float4*)(mrow + (size_t)rn * W + 4 * lane) =
                make_float4(mn[0], mn[1], mn[2], mn[3]);
        }

        if (i >= 4) {
            // vertical 5-tap for output row rn-2 (window holds rows rn-4..rn-1, mn = rn)
            float vv[4];
#pragma unroll
            for (int j = 0; j < 4; ++j)
                vv[j] = wb * (m0[j] + mn[j]) + wa * (m1[j] + m3[j]) + wc * m2[j];

            // horizontal 5-tap via adjacent-lane shuffles (x-reflect at edges)
            float l1 = __shfl_up(vv[3], 1);    // col c0-1
            float l2 = __shfl_up(vv[2], 1);    // col c0-2
            float r1 = __shfl_down(vv[0], 1);  // col c0+4
            float r2 = __shfl_down(vv[1], 1);  // col c0+5
            if (lane == 0)  { l1 = vv[1]; l2 = vv[2]; }
            if (lane == 63) { r1 = vv[2]; r2 = vv[1]; }
            float o0 = wc * vv[0] + wa * (l1 + vv[1])    + wb * (l2 + vv[2]);
            float o1 = wc * vv[1] + wa * (vv[0] + vv[2]) + wb * (l1 + vv[3]);
            float o2 = wc * vv[2] + wa * (vv[1] + vv[3]) + wb * (vv[0] + r1);
            float o3 = wc * vv[3] + wa * (vv[2] + r1)    + wb * (vv[1] + r2);
            gmax = fmaxf(gmax, fmaxf(fmaxf(o0, o1), fmaxf(o2, o3)));
        }

#pragma unroll
        for (int j = 0; j < 4; ++j) { m0[j] = m1[j]; m1[j] = m2[j]; m2[j] = m3[j]; m3[j] = mn[j]; }
    }

    // ---- wave max -> partial (no cross-wave sync needed) ----
#pragma unroll
    for (int off = 32; off > 0; off >>= 1)
        gmax = fmaxf(gmax, __shfl_down(gmax, off));
    if (lane == 0) part[bid * WAVES + w] = gmax;
}

__global__ void reduce_kernel(const float* __restrict__ part,
                              float* __restrict__ scores, int B) {
    int i = blockIdx.x * blockDim.x + threadIdx.x;
    if (i < B) {
        const int P = QH * WAVES;   // 16 partials per sample
        float m = part[P * i];
#pragma unroll
        for (int k = 1; k < P; ++k) m = fmaxf(m, part[P * i + k]);
        scores[i] = m;
    }
}

extern "C" void kernel_launch(void* const* d_in, const int* in_sizes, int n_in,
                              void* d_out, int out_size, void* d_ws, size_t ws_size,
                              hipStream_t stream) {
    const float* in0 = (const float*)d_in[0];
    const float* in1 = (const float*)d_in[1];
    const float* in2 = (const float*)d_in[2];
    const int B = in_sizes[0] / (64 * 64);

    float* scores = (float*)d_out;
    float* maps   = (float*)d_out + B;
    float* part   = (float*)d_ws;           // B*16 floats, fully rewritten each call

    hipLaunchKernelGGL(fused_kernel, dim3(B * QH), dim3(256), 0, stream,
                       in0, in1, in2, part, maps);
    hipLaunchKernelGGL(reduce_kernel, dim3((B + 255) / 256), dim3(256), 0, stream,
                       part, scores, B);
}